// Round 4
// baseline (4892.370 us; speedup 1.0000x reference)
//
#include <hip/hip_runtime.h>

#define DIM 2048
#define LEAK 0.2f

typedef __bf16 bf16x8 __attribute__((ext_vector_type(8)));
typedef float  f32x4  __attribute__((ext_vector_type(4)));
typedef unsigned int u32x4 __attribute__((ext_vector_type(4)));
typedef int    i32x4  __attribute__((ext_vector_type(4)));

static __device__ __forceinline__ unsigned short f2bf(float f) {
    unsigned int x = __float_as_uint(f);
    return (unsigned short)((x + 0x7fffu + ((x >> 16) & 1u)) >> 16);  // RNE
}
static __device__ __forceinline__ float bf2f(unsigned short h) {
    return __uint_as_float(((unsigned int)h) << 16);
}

static __device__ __forceinline__ void async16(const void* g, void* s) {
    __builtin_amdgcn_global_load_lds(
        (const __attribute__((address_space(1))) void*)g,
        (__attribute__((address_space(3))) void*)s, 16, 0, 0);
}

static __device__ __forceinline__ bf16x8 ld_bf16_frag(const char* p) {
    union { u32x4 u; bf16x8 v; } cv;
    cv.u = *(const u32x4*)p;   // ds_read_b128
    return cv.v;
}

// ---------------- prep kernels ----------------

__global__ __launch_bounds__(256) void split_kernel(
    const float* __restrict__ in,
    unsigned short* __restrict__ hi, unsigned short* __restrict__ lo) {
    int idx = blockIdx.x * 256 + threadIdx.x;
    float4 v = ((const float4*)in)[idx];
    ushort4 h, l;
    h.x = f2bf(v.x); l.x = f2bf(v.x - bf2f(h.x));
    h.y = f2bf(v.y); l.y = f2bf(v.y - bf2f(h.y));
    h.z = f2bf(v.z); l.z = f2bf(v.z - bf2f(h.z));
    h.w = f2bf(v.w); l.w = f2bf(v.w - bf2f(h.w));
    ((ushort4*)hi)[idx] = h;
    ((ushort4*)lo)[idx] = l;
}

__global__ __launch_bounds__(256) void transpose_split(
    const float* __restrict__ in,
    unsigned short* __restrict__ hiT, unsigned short* __restrict__ loT) {
    __shared__ float t[32][33];
    int bx = blockIdx.x, by = blockIdx.y;
    int tx = threadIdx.x & 31, ty4 = (threadIdx.x >> 5) << 2;
#pragma unroll
    for (int i = 0; i < 4; i++)
        t[ty4 + i][tx] = in[(size_t)(by * 32 + ty4 + i) * DIM + bx * 32 + tx];
    __syncthreads();
#pragma unroll
    for (int i = 0; i < 4; i++) {
        float v = t[tx][ty4 + i];
        size_t o = (size_t)(bx * 32 + ty4 + i) * DIM + by * 32 + tx;
        unsigned short h = f2bf(v);
        hiT[o] = h;
        loT[o] = f2bf(v - bf2f(h));
    }
}

__global__ __launch_bounds__(256) void transpose_i8(
    const float* __restrict__ in, signed char* __restrict__ outT) {
    __shared__ float t[32][33];
    int bx = blockIdx.x, by = blockIdx.y;
    int tx = threadIdx.x & 31, ty4 = (threadIdx.x >> 5) << 2;
#pragma unroll
    for (int i = 0; i < 4; i++)
        t[ty4 + i][tx] = in[(size_t)(by * 32 + ty4 + i) * DIM + bx * 32 + tx];
    __syncthreads();
#pragma unroll
    for (int i = 0; i < 4; i++)
        outT[(size_t)(bx * 32 + ty4 + i) * DIM + by * 32 + tx] =
            (signed char)t[tx][ty4 + i];
}

__global__ __launch_bounds__(256) void quant_split(
    const float* __restrict__ in,
    signed char* __restrict__ hi, signed char* __restrict__ lo) {
    int idx = blockIdx.x * 256 + threadIdx.x;
    float4 v = ((const float4*)in)[idx];
    char4 h, l;
    {
        int q = (int)rintf(v.x * 16384.f); q = q > 16383 ? 16383 : (q < -16383 ? -16383 : q);
        h.x = (signed char)(q >> 7); l.x = (signed char)(q & 127);
    }
    {
        int q = (int)rintf(v.y * 16384.f); q = q > 16383 ? 16383 : (q < -16383 ? -16383 : q);
        h.y = (signed char)(q >> 7); l.y = (signed char)(q & 127);
    }
    {
        int q = (int)rintf(v.z * 16384.f); q = q > 16383 ? 16383 : (q < -16383 ? -16383 : q);
        h.z = (signed char)(q >> 7); l.z = (signed char)(q & 127);
    }
    {
        int q = (int)rintf(v.w * 16384.f); q = q > 16383 ? 16383 : (q < -16383 ? -16383 : q);
        h.w = (signed char)(q >> 7); l.w = (signed char)(q & 127);
    }
    ((char4*)hi)[idx] = h;
    ((char4*)lo)[idx] = l;
}

// ---------------- bf16 dual-A GEMM (drive), tile 64x128, dbuf (R3) ----------------
template <int MODE>
__global__ __launch_bounds__(256) void gemm_bf16(
    const unsigned short* __restrict__ Ahi,
    const unsigned short* __restrict__ Alo,
    const unsigned short* __restrict__ BT,
    const float* __restrict__ Cin,
    const float* __restrict__ bias,
    float* __restrict__ Cout) {
    __shared__ alignas(16) char sA[2][16384];
    __shared__ alignas(16) char sB[2][16384];

    const int bid = blockIdx.x;
    const int xcd = bid & 7, slot = bid >> 3;
    const int tm = ((xcd >> 1) << 3) + (slot >> 3);
    const int tn = ((xcd & 1) << 3) + (slot & 7);
    const int row0 = tm << 6, col0 = tn << 7;

    const int tid = threadIdx.x;
    const int lane = tid & 63;
    const int quad = lane >> 4, l16 = lane & 15;
    const int wave = tid >> 6;
    const int wm = wave >> 1, wn = wave & 1;

    const unsigned short* a_src[4]; int a_dst[4];
    const unsigned short* b_src[4]; int b_dst[4];
#pragma unroll
    for (int i = 0; i < 4; i++) {
        int s = tid + 256 * i;
        {
            int r = s >> 4, g = (s >> 3) & 1, c = (s & 7) ^ (r & 7);
            a_src[i] = (g ? Alo : Ahi) + (size_t)(row0 + r) * DIM + c * 8;
            a_dst[i] = s * 16;
        }
        {
            int r = s >> 3, c = (s & 7) ^ (r & 7);
            b_src[i] = BT + (size_t)(col0 + r) * DIM + c * 8;
            b_dst[i] = s * 16;
        }
    }

    f32x4 acc[2][4] = {};

    auto stage = [&](int p, int k0) {
#pragma unroll
        for (int i = 0; i < 4; i++) {
            async16(a_src[i] + k0, sA[p] + a_dst[i]);
            async16(b_src[i] + k0, sB[p] + b_dst[i]);
        }
    };

    stage(0, 0);
    __syncthreads();
    for (int it = 0; it < 32; it++) {
        const int p = it & 1;
        if (it + 1 < 32) stage(1 - p, (it + 1) * 64);
#pragma unroll
        for (int kk = 0; kk < 2; kk++) {
            bf16x8 ah[2], al[2], bv[4];
#pragma unroll
            for (int i = 0; i < 2; i++) {
                const int r = (wm << 5) + (i << 4) + l16;
                const int cs = ((kk << 2) + quad) ^ (r & 7);
                ah[i] = ld_bf16_frag(sA[p] + ((r << 4) + cs) * 16);
                al[i] = ld_bf16_frag(sA[p] + ((r << 4) + 8 + cs) * 16);
            }
#pragma unroll
            for (int j = 0; j < 4; j++) {
                const int r = (wn << 6) + (j << 4) + l16;
                const int cs = ((kk << 2) + quad) ^ (r & 7);
                bv[j] = ld_bf16_frag(sB[p] + ((r << 3) + cs) * 16);
            }
#pragma unroll
            for (int i = 0; i < 2; i++)
#pragma unroll
                for (int j = 0; j < 4; j++) {
                    acc[i][j] = __builtin_amdgcn_mfma_f32_16x16x32_bf16(ah[i], bv[j], acc[i][j], 0, 0, 0);
                    acc[i][j] = __builtin_amdgcn_mfma_f32_16x16x32_bf16(al[i], bv[j], acc[i][j], 0, 0, 0);
                }
        }
        __syncthreads();
    }

#pragma unroll
    for (int i = 0; i < 2; i++) {
        const int rb = row0 + (wm << 5) + (i << 4) + (quad << 2);
#pragma unroll
        for (int j = 0; j < 4; j++) {
            const int c = col0 + (wn << 6) + (j << 4) + l16;
#pragma unroll
            for (int g = 0; g < 4; g++) {
                const size_t idx = (size_t)(rb + g) * DIM + c;
                if (MODE == 0) Cout[idx] = acc[i][j][g];
                else           Cout[idx] = Cin[idx] + acc[i][j][g] + bias[c];
            }
        }
    }
}

// ---------------- i8 recurrence step: barrier-free streaming ----------------
// One wave per block, wave-tile 32(m) x 64(n), fragments loaded directly
// global(L2) -> VGPR as global_load_dwordx4 (A-frag pattern: lane=quad*16+l16
// reads rows row0+i*16+l16, bytes [k0+quad*16, +16) -- 16 rows x 64B segments,
// coalesced). No LDS, no __syncthreads: compiler pipelines loads across
// k-iters with fine-grained vmcnt (the pattern the 2-barrier loop couldn't).
__global__ __launch_bounds__(64, 2) void step_i8(
    const signed char* __restrict__ Ah,
    const signed char* __restrict__ Al,
    const signed char* __restrict__ BT,
    const float* __restrict__ drive,
    float* __restrict__ out,
    signed char* __restrict__ Oh,
    signed char* __restrict__ Ol,
    int write_f32) {
    // XCD swizzle: tiles 64(m) x 32(n); each XCD owns a 16x16-tile region
    // (A-slice 2MB + B-slice 2MB = one 4MiB XCD L2).
    const int bid = blockIdx.x;
    const int xcd = bid & 7, slot = bid >> 3;            // 256 slots/XCD
    const int tm = ((xcd >> 1) << 4) + (slot >> 4);      // 0..63
    const int tn = ((xcd & 1) << 4) + (slot & 15);       // 0..31
    const int row0 = tm << 5, col0 = tn << 6;

    const int lane = threadIdx.x;
    const int quad = lane >> 4, l16 = lane & 15;

    const size_t aoff0 = (size_t)(row0 + l16) * DIM + (quad << 4);
    const size_t aoff1 = aoff0 + (size_t)16 * DIM;
    size_t boff[4];
#pragma unroll
    for (int j = 0; j < 4; j++)
        boff[j] = (size_t)(col0 + (j << 4) + l16) * DIM + (quad << 4);

    i32x4 acch[2][4] = {};
    i32x4 accl[2][4] = {};

#pragma unroll 2
    for (int k0 = 0; k0 < DIM; k0 += 64) {
        i32x4 a0h = *(const i32x4*)(Ah + aoff0 + k0);
        i32x4 a1h = *(const i32x4*)(Ah + aoff1 + k0);
        i32x4 a0l = *(const i32x4*)(Al + aoff0 + k0);
        i32x4 a1l = *(const i32x4*)(Al + aoff1 + k0);
        i32x4 b0  = *(const i32x4*)(BT + boff[0] + k0);
        i32x4 b1  = *(const i32x4*)(BT + boff[1] + k0);
        i32x4 b2  = *(const i32x4*)(BT + boff[2] + k0);
        i32x4 b3  = *(const i32x4*)(BT + boff[3] + k0);

        acch[0][0] = __builtin_amdgcn_mfma_i32_16x16x64_i8(a0h, b0, acch[0][0], 0, 0, 0);
        acch[0][1] = __builtin_amdgcn_mfma_i32_16x16x64_i8(a0h, b1, acch[0][1], 0, 0, 0);
        acch[0][2] = __builtin_amdgcn_mfma_i32_16x16x64_i8(a0h, b2, acch[0][2], 0, 0, 0);
        acch[0][3] = __builtin_amdgcn_mfma_i32_16x16x64_i8(a0h, b3, acch[0][3], 0, 0, 0);
        acch[1][0] = __builtin_amdgcn_mfma_i32_16x16x64_i8(a1h, b0, acch[1][0], 0, 0, 0);
        acch[1][1] = __builtin_amdgcn_mfma_i32_16x16x64_i8(a1h, b1, acch[1][1], 0, 0, 0);
        acch[1][2] = __builtin_amdgcn_mfma_i32_16x16x64_i8(a1h, b2, acch[1][2], 0, 0, 0);
        acch[1][3] = __builtin_amdgcn_mfma_i32_16x16x64_i8(a1h, b3, acch[1][3], 0, 0, 0);
        accl[0][0] = __builtin_amdgcn_mfma_i32_16x16x64_i8(a0l, b0, accl[0][0], 0, 0, 0);
        accl[0][1] = __builtin_amdgcn_mfma_i32_16x16x64_i8(a0l, b1, accl[0][1], 0, 0, 0);
        accl[0][2] = __builtin_amdgcn_mfma_i32_16x16x64_i8(a0l, b2, accl[0][2], 0, 0, 0);
        accl[0][3] = __builtin_amdgcn_mfma_i32_16x16x64_i8(a0l, b3, accl[0][3], 0, 0, 0);
        accl[1][0] = __builtin_amdgcn_mfma_i32_16x16x64_i8(a1l, b0, accl[1][0], 0, 0, 0);
        accl[1][1] = __builtin_amdgcn_mfma_i32_16x16x64_i8(a1l, b1, accl[1][1], 0, 0, 0);
        accl[1][2] = __builtin_amdgcn_mfma_i32_16x16x64_i8(a1l, b2, accl[1][2], 0, 0, 0);
        accl[1][3] = __builtin_amdgcn_mfma_i32_16x16x64_i8(a1l, b3, accl[1][3], 0, 0, 0);
    }

    // C/D layout: col = lane&15, row = quad*4 + g
#pragma unroll
    for (int i = 0; i < 2; i++) {
        const int rb = row0 + (i << 4) + (quad << 2);
#pragma unroll
        for (int j = 0; j < 4; j++) {
            const int c = col0 + (j << 4) + l16;
#pragma unroll
            for (int g = 0; g < 4; g++) {
                const size_t idx = (size_t)(rb + g) * DIM + c;
                int prod = acch[i][j][g] * 128 + accl[i][j][g];   // exact int
                float y = drive[idx] + (float)prod * (1.0f / 16384.0f);
                float sold = (float)((int)Ah[idx] * 128 + (int)Al[idx]) * (1.0f / 16384.0f);
                float e = __expf(2.0f * y);
                float th = 1.0f - 2.0f / (e + 1.0f);
                float s = (1.0f - LEAK) * sold + LEAK * th;
                if (write_f32) out[idx] = s;
                int q = (int)rintf(s * 16384.f);
                q = q > 16383 ? 16383 : (q < -16383 ? -16383 : q);
                Oh[idx] = (signed char)(q >> 7);
                Ol[idx] = (signed char)(q & 127);
            }
        }
    }
}

extern "C" void kernel_launch(void* const* d_in, const int* in_sizes, int n_in,
                              void* d_out, int out_size, void* d_ws, size_t ws_size,
                              hipStream_t stream) {
    const float* x    = (const float*)d_in[0];
    const float* wgt  = (const float*)d_in[1];
    const float* adj  = (const float*)d_in[2];
    const float* bias = (const float*)d_in[3];
    const float* st0  = (const float*)d_in[4];
    float* out = (float*)d_out;

    const size_t NE = (size_t)DIM * DIM;
    signed char* adjT = (signed char*)d_ws;
    float* drive = (float*)(adjT + NE);
    unsigned short* bufA = (unsigned short*)(drive + NE);
    unsigned short* bufB = bufA + NE;
    unsigned short* bufC = bufB + NE;
    unsigned short* bufD = bufC + NE;
    signed char* h1 = (signed char*)bufA;
    signed char* l1 = h1 + NE;
    signed char* h2 = l1 + NE;
    signed char* l2 = h2 + NE;

    dim3 blk(256);
    transpose_split<<<dim3(64, 64), blk, 0, stream>>>(wgt, bufC, bufD);
    split_kernel<<<dim3(4096), blk, 0, stream>>>(x, bufA, bufB);
    transpose_i8<<<dim3(64, 64), blk, 0, stream>>>(adj, adjT);

    gemm_bf16<0><<<dim3(512), blk, 0, stream>>>(bufA, bufB, bufC, (const float*)0,
                                                (const float*)0, drive);
    gemm_bf16<1><<<dim3(512), blk, 0, stream>>>(bufA, bufB, bufD, drive, bias, drive);

    quant_split<<<dim3(4096), blk, 0, stream>>>(st0, h1, l1);

    signed char* hi = h1; signed char* li = l1;
    signed char* ho = h2; signed char* lo = l2;
    for (int t = 0; t < 64; t++) {
        step_i8<<<dim3(2048), dim3(64), 0, stream>>>(hi, li, adjT, drive, out,
                                                     ho, lo, (t == 63) ? 1 : 0);
        signed char* th = hi; hi = ho; ho = th;
        signed char* tl = li; li = lo; lo = tl;
    }
}

// Round 5
// 4655.717 us; speedup vs baseline: 1.0508x; 1.0508x over previous
//
#include <hip/hip_runtime.h>

#define DIM 2048
#define LEAK 0.2f

typedef __bf16 bf16x8 __attribute__((ext_vector_type(8)));
typedef float  f32x4  __attribute__((ext_vector_type(4)));
typedef unsigned int u32x4 __attribute__((ext_vector_type(4)));
typedef int    i32x4  __attribute__((ext_vector_type(4)));

static __device__ __forceinline__ unsigned short f2bf(float f) {
    unsigned int x = __float_as_uint(f);
    return (unsigned short)((x + 0x7fffu + ((x >> 16) & 1u)) >> 16);  // RNE
}
static __device__ __forceinline__ float bf2f(unsigned short h) {
    return __uint_as_float(((unsigned int)h) << 16);
}

static __device__ __forceinline__ void async16(const void* g, void* s) {
    __builtin_amdgcn_global_load_lds(
        (const __attribute__((address_space(1))) void*)g,
        (__attribute__((address_space(3))) void*)s, 16, 0, 0);
}

static __device__ __forceinline__ bf16x8 ld_bf16_frag(const char* p) {
    union { u32x4 u; bf16x8 v; } cv;
    cv.u = *(const u32x4*)p;   // ds_read_b128
    return cv.v;
}

// ---------------- prep kernels ----------------

__global__ __launch_bounds__(256) void split_kernel(
    const float* __restrict__ in,
    unsigned short* __restrict__ hi, unsigned short* __restrict__ lo) {
    int idx = blockIdx.x * 256 + threadIdx.x;
    float4 v = ((const float4*)in)[idx];
    ushort4 h, l;
    h.x = f2bf(v.x); l.x = f2bf(v.x - bf2f(h.x));
    h.y = f2bf(v.y); l.y = f2bf(v.y - bf2f(h.y));
    h.z = f2bf(v.z); l.z = f2bf(v.z - bf2f(h.z));
    h.w = f2bf(v.w); l.w = f2bf(v.w - bf2f(h.w));
    ((ushort4*)hi)[idx] = h;
    ((ushort4*)lo)[idx] = l;
}

__global__ __launch_bounds__(256) void transpose_split(
    const float* __restrict__ in,
    unsigned short* __restrict__ hiT, unsigned short* __restrict__ loT) {
    __shared__ float t[32][33];
    int bx = blockIdx.x, by = blockIdx.y;
    int tx = threadIdx.x & 31, ty4 = (threadIdx.x >> 5) << 2;
#pragma unroll
    for (int i = 0; i < 4; i++)
        t[ty4 + i][tx] = in[(size_t)(by * 32 + ty4 + i) * DIM + bx * 32 + tx];
    __syncthreads();
#pragma unroll
    for (int i = 0; i < 4; i++) {
        float v = t[tx][ty4 + i];
        size_t o = (size_t)(bx * 32 + ty4 + i) * DIM + by * 32 + tx;
        unsigned short h = f2bf(v);
        hiT[o] = h;
        loT[o] = f2bf(v - bf2f(h));
    }
}

__global__ __launch_bounds__(256) void transpose_i8(
    const float* __restrict__ in, signed char* __restrict__ outT) {
    __shared__ float t[32][33];
    int bx = blockIdx.x, by = blockIdx.y;
    int tx = threadIdx.x & 31, ty4 = (threadIdx.x >> 5) << 2;
#pragma unroll
    for (int i = 0; i < 4; i++)
        t[ty4 + i][tx] = in[(size_t)(by * 32 + ty4 + i) * DIM + bx * 32 + tx];
    __syncthreads();
#pragma unroll
    for (int i = 0; i < 4; i++)
        outT[(size_t)(bx * 32 + ty4 + i) * DIM + by * 32 + tx] =
            (signed char)t[tx][ty4 + i];
}

__global__ __launch_bounds__(256) void quant_split(
    const float* __restrict__ in,
    signed char* __restrict__ hi, signed char* __restrict__ lo) {
    int idx = blockIdx.x * 256 + threadIdx.x;
    float4 v = ((const float4*)in)[idx];
    char4 h, l;
    {
        int q = (int)rintf(v.x * 16384.f); q = q > 16383 ? 16383 : (q < -16383 ? -16383 : q);
        h.x = (signed char)(q >> 7); l.x = (signed char)(q & 127);
    }
    {
        int q = (int)rintf(v.y * 16384.f); q = q > 16383 ? 16383 : (q < -16383 ? -16383 : q);
        h.y = (signed char)(q >> 7); l.y = (signed char)(q & 127);
    }
    {
        int q = (int)rintf(v.z * 16384.f); q = q > 16383 ? 16383 : (q < -16383 ? -16383 : q);
        h.z = (signed char)(q >> 7); l.z = (signed char)(q & 127);
    }
    {
        int q = (int)rintf(v.w * 16384.f); q = q > 16383 ? 16383 : (q < -16383 ? -16383 : q);
        h.w = (signed char)(q >> 7); l.w = (signed char)(q & 127);
    }
    ((char4*)hi)[idx] = h;
    ((char4*)lo)[idx] = l;
}

// ---------------- bf16 dual-A GEMM (drive), tile 64x128, dbuf (R3) ----------------
template <int MODE>
__global__ __launch_bounds__(256) void gemm_bf16(
    const unsigned short* __restrict__ Ahi,
    const unsigned short* __restrict__ Alo,
    const unsigned short* __restrict__ BT,
    const float* __restrict__ Cin,
    const float* __restrict__ bias,
    float* __restrict__ Cout) {
    __shared__ alignas(16) char sA[2][16384];
    __shared__ alignas(16) char sB[2][16384];

    const int bid = blockIdx.x;
    const int xcd = bid & 7, slot = bid >> 3;
    const int tm = ((xcd >> 1) << 3) + (slot >> 3);
    const int tn = ((xcd & 1) << 3) + (slot & 7);
    const int row0 = tm << 6, col0 = tn << 7;

    const int tid = threadIdx.x;
    const int lane = tid & 63;
    const int quad = lane >> 4, l16 = lane & 15;
    const int wave = tid >> 6;
    const int wm = wave >> 1, wn = wave & 1;

    const unsigned short* a_src[4]; int a_dst[4];
    const unsigned short* b_src[4]; int b_dst[4];
#pragma unroll
    for (int i = 0; i < 4; i++) {
        int s = tid + 256 * i;
        {
            int r = s >> 4, g = (s >> 3) & 1, c = (s & 7) ^ (r & 7);
            a_src[i] = (g ? Alo : Ahi) + (size_t)(row0 + r) * DIM + c * 8;
            a_dst[i] = s * 16;
        }
        {
            int r = s >> 3, c = (s & 7) ^ (r & 7);
            b_src[i] = BT + (size_t)(col0 + r) * DIM + c * 8;
            b_dst[i] = s * 16;
        }
    }

    f32x4 acc[2][4] = {};

    auto stage = [&](int p, int k0) {
#pragma unroll
        for (int i = 0; i < 4; i++) {
            async16(a_src[i] + k0, sA[p] + a_dst[i]);
            async16(b_src[i] + k0, sB[p] + b_dst[i]);
        }
    };

    stage(0, 0);
    __syncthreads();
    for (int it = 0; it < 32; it++) {
        const int p = it & 1;
        if (it + 1 < 32) stage(1 - p, (it + 1) * 64);
#pragma unroll
        for (int kk = 0; kk < 2; kk++) {
            bf16x8 ah[2], al[2], bv[4];
#pragma unroll
            for (int i = 0; i < 2; i++) {
                const int r = (wm << 5) + (i << 4) + l16;
                const int cs = ((kk << 2) + quad) ^ (r & 7);
                ah[i] = ld_bf16_frag(sA[p] + ((r << 4) + cs) * 16);
                al[i] = ld_bf16_frag(sA[p] + ((r << 4) + 8 + cs) * 16);
            }
#pragma unroll
            for (int j = 0; j < 4; j++) {
                const int r = (wn << 6) + (j << 4) + l16;
                const int cs = ((kk << 2) + quad) ^ (r & 7);
                bv[j] = ld_bf16_frag(sB[p] + ((r << 3) + cs) * 16);
            }
#pragma unroll
            for (int i = 0; i < 2; i++)
#pragma unroll
                for (int j = 0; j < 4; j++) {
                    acc[i][j] = __builtin_amdgcn_mfma_f32_16x16x32_bf16(ah[i], bv[j], acc[i][j], 0, 0, 0);
                    acc[i][j] = __builtin_amdgcn_mfma_f32_16x16x32_bf16(al[i], bv[j], acc[i][j], 0, 0, 0);
                }
        }
        __syncthreads();
    }

#pragma unroll
    for (int i = 0; i < 2; i++) {
        const int rb = row0 + (wm << 5) + (i << 4) + (quad << 2);
#pragma unroll
        for (int j = 0; j < 4; j++) {
            const int c = col0 + (wn << 6) + (j << 4) + l16;
#pragma unroll
            for (int g = 0; g < 4; g++) {
                const size_t idx = (size_t)(rb + g) * DIM + c;
                if (MODE == 0) Cout[idx] = acc[i][j][g];
                else           Cout[idx] = Cin[idx] + acc[i][j][g] + bias[c];
            }
        }
    }
}

// ---------------- i8 step: streaming, explicit register pipeline ----------------
// One wave/block, wave-tile 32(m) x 64(n). Fragments global(L2)->VGPR.
// Manually unrolled x2 k-loop with two named 8-fragment buffers: phase k+1's
// loads issue BEFORE phase k's MFMAs consume their buffer, so the compiler
// keeps 8 loads in flight (R4's single-buffer body got VGPR=56 -> serialized).
// XCD swizzle by m-stripe: each XCD owns 8 tile-rows x all n -> full 128B
// write lines per XCD (fixes R4's partial-line WRITE_SIZE blowup).
__global__ __launch_bounds__(64) void step_i8(
    const signed char* __restrict__ Ah,
    const signed char* __restrict__ Al,
    const signed char* __restrict__ BT,
    const float* __restrict__ drive,
    float* __restrict__ out,
    signed char* __restrict__ Oh,
    signed char* __restrict__ Ol,
    int write_f32) {
    const int bid = blockIdx.x;
    const int xcd = bid & 7, slot = bid >> 3;       // 256 slots/XCD
    const int tm = (xcd << 3) + (slot >> 5);        // 0..63  (8 tile-rows/XCD)
    const int tn = slot & 31;                        // 0..31  (all n in-XCD)
    const int row0 = tm << 5, col0 = tn << 6;

    const int lane = threadIdx.x;
    const int quad = lane >> 4, l16 = lane & 15;

    const signed char* pa0h = Ah + (size_t)(row0 + l16) * DIM + (quad << 4);
    const signed char* pa1h = pa0h + (size_t)16 * DIM;
    const signed char* pa0l = Al + (size_t)(row0 + l16) * DIM + (quad << 4);
    const signed char* pa1l = pa0l + (size_t)16 * DIM;
    const signed char* pb0 = BT + (size_t)(col0 + l16) * DIM + (quad << 4);
    const signed char* pb1 = pb0 + (size_t)16 * DIM;
    const signed char* pb2 = pb0 + (size_t)32 * DIM;
    const signed char* pb3 = pb0 + (size_t)48 * DIM;

    i32x4 acch[2][4] = {};
    i32x4 accl[2][4] = {};

    i32x4 A0[4], B0[4], A1[4], B1[4];

    // prologue: phase-0 fragments (k=0)
    A0[0] = *(const i32x4*)(pa0h); A0[1] = *(const i32x4*)(pa1h);
    A0[2] = *(const i32x4*)(pa0l); A0[3] = *(const i32x4*)(pa1l);
    B0[0] = *(const i32x4*)(pb0);  B0[1] = *(const i32x4*)(pb1);
    B0[2] = *(const i32x4*)(pb2);  B0[3] = *(const i32x4*)(pb3);

#define MFMA16(F)                                                                    \
    do {                                                                             \
        acch[0][0] = __builtin_amdgcn_mfma_i32_16x16x64_i8(F[0], F##B[0], acch[0][0], 0, 0, 0); \
        acch[0][1] = __builtin_amdgcn_mfma_i32_16x16x64_i8(F[0], F##B[1], acch[0][1], 0, 0, 0); \
        acch[0][2] = __builtin_amdgcn_mfma_i32_16x16x64_i8(F[0], F##B[2], acch[0][2], 0, 0, 0); \
        acch[0][3] = __builtin_amdgcn_mfma_i32_16x16x64_i8(F[0], F##B[3], acch[0][3], 0, 0, 0); \
        acch[1][0] = __builtin_amdgcn_mfma_i32_16x16x64_i8(F[1], F##B[0], acch[1][0], 0, 0, 0); \
        acch[1][1] = __builtin_amdgcn_mfma_i32_16x16x64_i8(F[1], F##B[1], acch[1][1], 0, 0, 0); \
        acch[1][2] = __builtin_amdgcn_mfma_i32_16x16x64_i8(F[1], F##B[2], acch[1][2], 0, 0, 0); \
        acch[1][3] = __builtin_amdgcn_mfma_i32_16x16x64_i8(F[1], F##B[3], acch[1][3], 0, 0, 0); \
        accl[0][0] = __builtin_amdgcn_mfma_i32_16x16x64_i8(F[2], F##B[0], accl[0][0], 0, 0, 0); \
        accl[0][1] = __builtin_amdgcn_mfma_i32_16x16x64_i8(F[2], F##B[1], accl[0][1], 0, 0, 0); \
        accl[0][2] = __builtin_amdgcn_mfma_i32_16x16x64_i8(F[2], F##B[2], accl[0][2], 0, 0, 0); \
        accl[0][3] = __builtin_amdgcn_mfma_i32_16x16x64_i8(F[2], F##B[3], accl[0][3], 0, 0, 0); \
        accl[1][0] = __builtin_amdgcn_mfma_i32_16x16x64_i8(F[3], F##B[0], accl[1][0], 0, 0, 0); \
        accl[1][1] = __builtin_amdgcn_mfma_i32_16x16x64_i8(F[3], F##B[1], accl[1][1], 0, 0, 0); \
        accl[1][2] = __builtin_amdgcn_mfma_i32_16x16x64_i8(F[3], F##B[2], accl[1][2], 0, 0, 0); \
        accl[1][3] = __builtin_amdgcn_mfma_i32_16x16x64_i8(F[3], F##B[3], accl[1][3], 0, 0, 0); \
    } while (0)
#define A0B B0
#define A1B B1

#pragma unroll 1
    for (int k0 = 0; k0 < DIM; k0 += 128) {
        // issue phase-1 loads (k0+64), then consume phase-0
        A1[0] = *(const i32x4*)(pa0h + k0 + 64); A1[1] = *(const i32x4*)(pa1h + k0 + 64);
        A1[2] = *(const i32x4*)(pa0l + k0 + 64); A1[3] = *(const i32x4*)(pa1l + k0 + 64);
        B1[0] = *(const i32x4*)(pb0 + k0 + 64);  B1[1] = *(const i32x4*)(pb1 + k0 + 64);
        B1[2] = *(const i32x4*)(pb2 + k0 + 64);  B1[3] = *(const i32x4*)(pb3 + k0 + 64);
        MFMA16(A0);
        // issue next phase-0 loads (k0+128), then consume phase-1
        if (k0 + 128 < DIM) {
            A0[0] = *(const i32x4*)(pa0h + k0 + 128); A0[1] = *(const i32x4*)(pa1h + k0 + 128);
            A0[2] = *(const i32x4*)(pa0l + k0 + 128); A0[3] = *(const i32x4*)(pa1l + k0 + 128);
            B0[0] = *(const i32x4*)(pb0 + k0 + 128);  B0[1] = *(const i32x4*)(pb1 + k0 + 128);
            B0[2] = *(const i32x4*)(pb2 + k0 + 128);  B0[3] = *(const i32x4*)(pb3 + k0 + 128);
        }
        MFMA16(A1);
    }
#undef MFMA16
#undef A0B
#undef A1B

    // epilogue: C/D layout col = lane&15, row = quad*4 + g  (verified R2-R4)
#pragma unroll
    for (int i = 0; i < 2; i++) {
        const int rb = row0 + (i << 4) + (quad << 2);
#pragma unroll
        for (int j = 0; j < 4; j++) {
            const int c = col0 + (j << 4) + l16;
#pragma unroll
            for (int g = 0; g < 4; g++) {
                const size_t idx = (size_t)(rb + g) * DIM + c;
                int prod = acch[i][j][g] * 128 + accl[i][j][g];   // exact int
                float y = drive[idx] + (float)prod * (1.0f / 16384.0f);
                float sold = (float)((int)Ah[idx] * 128 + (int)Al[idx]) * (1.0f / 16384.0f);
                float e = __expf(2.0f * y);
                float th = 1.0f - 2.0f / (e + 1.0f);
                float s = (1.0f - LEAK) * sold + LEAK * th;
                if (write_f32) out[idx] = s;
                int q = (int)rintf(s * 16384.f);
                q = q > 16383 ? 16383 : (q < -16383 ? -16383 : q);
                Oh[idx] = (signed char)(q >> 7);
                Ol[idx] = (signed char)(q & 127);
            }
        }
    }
}

extern "C" void kernel_launch(void* const* d_in, const int* in_sizes, int n_in,
                              void* d_out, int out_size, void* d_ws, size_t ws_size,
                              hipStream_t stream) {
    const float* x    = (const float*)d_in[0];
    const float* wgt  = (const float*)d_in[1];
    const float* adj  = (const float*)d_in[2];
    const float* bias = (const float*)d_in[3];
    const float* st0  = (const float*)d_in[4];
    float* out = (float*)d_out;

    const size_t NE = (size_t)DIM * DIM;
    signed char* adjT = (signed char*)d_ws;
    float* drive = (float*)(adjT + NE);
    unsigned short* bufA = (unsigned short*)(drive + NE);
    unsigned short* bufB = bufA + NE;
    unsigned short* bufC = bufB + NE;
    unsigned short* bufD = bufC + NE;
    signed char* h1 = (signed char*)bufA;
    signed char* l1 = h1 + NE;
    signed char* h2 = l1 + NE;
    signed char* l2 = h2 + NE;

    dim3 blk(256);
    transpose_split<<<dim3(64, 64), blk, 0, stream>>>(wgt, bufC, bufD);
    split_kernel<<<dim3(4096), blk, 0, stream>>>(x, bufA, bufB);
    transpose_i8<<<dim3(64, 64), blk, 0, stream>>>(adj, adjT);

    gemm_bf16<0><<<dim3(512), blk, 0, stream>>>(bufA, bufB, bufC, (const float*)0,
                                                (const float*)0, drive);
    gemm_bf16<1><<<dim3(512), blk, 0, stream>>>(bufA, bufB, bufD, drive, bias, drive);

    quant_split<<<dim3(4096), blk, 0, stream>>>(st0, h1, l1);

    signed char* hi = h1; signed char* li = l1;
    signed char* ho = h2; signed char* lo = l2;
    for (int t = 0; t < 64; t++) {
        step_i8<<<dim3(2048), dim3(64), 0, stream>>>(hi, li, adjT, drive, out,
                                                     ho, lo, (t == 63) ? 1 : 0);
        signed char* th = hi; hi = ho; ho = th;
        signed char* tl = li; li = lo; lo = tl;
    }
}